// Round 4
// baseline (226.103 us; speedup 1.0000x reference)
//
#include <hip/hip_runtime.h>
#include <stdint.h>

typedef unsigned short u16;
typedef unsigned int u32;
typedef __attribute__((ext_vector_type(8))) __bf16 bf16x8;
typedef __attribute__((ext_vector_type(4))) float f32x4;

#define N_IMG 64
#define C_IN  64
#define HW_IN 3136   // 56*56
#define W_IN  56
#define C_OUT 128
#define OH    54
#define OW    54
#define SPI   2916   // 54*54
#define KTOT  576    // C_IN*9

typedef __attribute__((address_space(3))) unsigned int lds_uint;
typedef __attribute__((address_space(1))) unsigned int gbl_uint;

__device__ __forceinline__ void load16_to_lds(const u16* g, u16* l) {
  // lane i of the wave writes LDS base + i*16 bytes; g is per-lane.
  __builtin_amdgcn_global_load_lds((const gbl_uint*)g, (lds_uint*)l, 16, 0, 0);
}

__device__ inline u16 f32_bf16_rne(float f) {
  unsigned u = __float_as_uint(f);
  u = (u + 0x7FFFu + ((u >> 16) & 1u)) >> 16;
  return (u16)u;
}

// One launch does both conversions.
//  blockIdx.x < 49 : x NCHW fp32 -> xt NHWC bf16 (clip+trunc; ints exact in bf16)
//  blockIdx.x == 49: w OIHW fp32 -> wtT[co][(kh*3+kw)*64+ci] bf16
__global__ __launch_bounds__(256) void convert_xw(const float* __restrict__ x,
                                                  const float* __restrict__ w,
                                                  u16* __restrict__ xt,
                                                  u16* __restrict__ wtT) {
  if (blockIdx.x == 49) {
    int o = blockIdx.y * 256 + threadIdx.x;
    #pragma unroll
    for (int it = 0; it < 5; it++) {
      int oo = o + it * 16384;
      if (oo < C_OUT * KTOT) {
        int co = oo / KTOT;
        int k  = oo - co * KTOT;
        int t2 = k >> 6, ci = k & 63;
        wtT[oo] = f32_bf16_rne(w[co * KTOT + ci * 9 + t2]);
      }
    }
    return;
  }
  __shared__ u16 tile[64][65];   // pad 65 (odd) -> conflict-free both phases
  int t  = threadIdx.x;
  int tx = t & 63, ty = t >> 6;
  int n  = blockIdx.y;
  int s0 = blockIdx.x * 64;
  const float* xp = x + (size_t)n * C_IN * HW_IN + s0;
  #pragma unroll
  for (int i = ty; i < 64; i += 4) {           // i = ci row; 256 B coalesced read
    float v = xp[i * HW_IN + tx];
    v = fminf(fmaxf(v, -128.f), 127.f);
    v = truncf(v);                             // == (float)(int)v here
    tile[i][tx] = (u16)(__float_as_uint(v) >> 16);  // exact: ints |v|<=128 in bf16
  }
  __syncthreads();
  u32* op = (u32*)(xt + (size_t)n * HW_IN * C_IN) + (size_t)s0 * 32;
  #pragma unroll
  for (int j = 0; j < 8; j++) {                // packed u32 writes: 2x128 B per wave
    int sp = j * 8 + ty * 2 + (tx >> 5);
    int cp = tx & 31;
    u32 lo = tile[2 * cp][sp];
    u32 hi = tile[2 * cp + 1][sp];
    op[sp * 32 + cp] = lo | (hi << 16);
  }
}

// Implicit GEMM, halo-reuse form: block = (img, oh-pair) -> 128 couts x
// (2 output rows x 64 padded ow). The 4 needed input rows (28.6 KB) are DMA'd
// to LDS ONCE; all 9 taps x 2 k-slices then run with ZERO barriers. Weights
// (147 KB, shared by all blocks) are read directly from global (L1/L2-hot)
// as 16 B fragments with compile-time offsets.
__global__ __launch_bounds__(256, 3) void conv_gemm(
    const u16* __restrict__ xt, const u16* __restrict__ wtT,
    const float* __restrict__ bias, float* __restrict__ y)
{
  // 30208 B: 4 rows x 56 px x 128 B = 28672 staged (+1280 B slack read by dead
  // lanes ow>=54, +256 pad). Overlaid by the 27648 B fp32 epilogue buffer.
  __shared__ alignas(16) u16 lds[15104];

  int tid  = threadIdx.x;
  int wv   = tid >> 6;
  int lane = tid & 63;
  int ln   = lane & 15;
  int q    = lane >> 4;
  int wy   = wv >> 1;            // cout half (0: co 0-63, 1: co 64-127)
  int wx   = wv & 1;             // which output row of the pair

  int n   = blockIdx.y;
  int oh0 = blockIdx.x * 2;

  // ---- stage input rows oh0..oh0+3 (wave wv does row wv; 7 DMAs of 1 KB) ----
  // LDS layout: [row][col][ci-group g'], g' = g ^ (col&7)  (XOR-16B swizzle,
  // applied on the SOURCE side to respect the DMA's contiguous-dest rule).
  {
    const u16* src = xt + ((size_t)n * HW_IN + (size_t)(oh0 + wv) * W_IN) * C_IN;
    u16* dst = lds + wv * (W_IN * C_IN);
    #pragma unroll
    for (int it = 0; it < 7; it++) {
      int gidx = it * 64 + lane;           // dest 16B-group within row
      int col  = gidx >> 3, gs = gidx & 7;
      int sgrp = col * 8 + (gs ^ (col & 7));
      load16_to_lds(src + sgrp * 8, dst + it * 512);
    }
  }

  // ---- per-lane invariant addresses ----
  int wbase[4];                  // u16 index into wtT
  #pragma unroll
  for (int mt = 0; mt < 4; mt++)
    wbase[mt] = (wy * 64 + mt * 16 + ln) * KTOT + q * 8;

  int poff[3][2];                // byte offset into lds (kh/nt folded as imm)
  #pragma unroll
  for (int kw = 0; kw < 3; kw++)
    #pragma unroll
    for (int s = 0; s < 2; s++)
      poff[kw][s] = (wx * W_IN + ln + kw) * 128
                  + (((s * 4 + q) ^ ((ln + kw) & 7)) * 16);

  f32x4 acc[4][4];
  #pragma unroll
  for (int mt = 0; mt < 4; mt++)
    #pragma unroll
    for (int nt = 0; nt < 4; nt++)
      acc[mt][nt] = (f32x4){0.f, 0.f, 0.f, 0.f};

  __syncthreads();   // staging complete (each wave drains its own vmcnt first)

  // ---- K-loop: 9 taps x 2 slices, no barriers ----
  const char* ldsb = (const char*)lds;
  #pragma unroll
  for (int tap = 0; tap < 9; tap++) {
    const int kh = tap / 3, kw = tap - kh * 3;
    #pragma unroll
    for (int s = 0; s < 2; s++) {
      bf16x8 wf[4], pf[4];
      #pragma unroll
      for (int mt = 0; mt < 4; mt++)
        wf[mt] = *(const bf16x8*)(wtT + wbase[mt] + tap * 64 + s * 32);
      #pragma unroll
      for (int nt = 0; nt < 4; nt++)
        pf[nt] = *(const bf16x8*)(ldsb + poff[kw][s] + kh * 7168 + nt * 2048);
      #pragma unroll
      for (int mt = 0; mt < 4; mt++)
        #pragma unroll
        for (int nt = 0; nt < 4; nt++)
          acc[mt][nt] = __builtin_amdgcn_mfma_f32_16x16x32_bf16(
              wf[mt], pf[nt], acc[mt][nt], 0, 0, 0);
    }
  }

  // ---- epilogue: two phases through a 64co x 108 fp32 bounce buffer.
  // stride 108: 4*108 mod 32 = 16 -> 2-way (free) on dump; reads conflict-free.
  // Stores: per (co, row-pair) a contiguous 432 B run (256 B + 176 B insts).
  float* wbuf = (float*)lds;
  size_t ybase_blk = (size_t)n * C_OUT * SPI + (size_t)oh0 * OW;

  #pragma unroll
  for (int phase = 0; phase < 2; phase++) {
    __syncthreads();             // pixels done / previous phase's reads done
    if (wy == phase) {
      #pragma unroll
      for (int mt = 0; mt < 4; mt++)
        #pragma unroll
        for (int nt = 0; nt < 4; nt++) {
          int ow = nt * 16 + ln;
          if (ow < OW) {
            #pragma unroll
            for (int r = 0; r < 4; r++)
              wbuf[(mt * 16 + q * 4 + r) * 108 + wx * OW + ow] = acc[mt][nt][r];
          }
        }
    }
    __syncthreads();
    #pragma unroll
    for (int i = 0; i < 16; i++) {
      int col = wv * 16 + i;               // co within phase
      int cog = phase * 64 + col;
      float b = bias[cog];
      size_t yb = ybase_blk + (size_t)cog * SPI;
      #pragma unroll
      for (int it = 0; it < 2; it++) {
        int idx = it * 64 + lane;
        if (idx < 108) y[yb + idx] = wbuf[col * 108 + idx] + b;
      }
    }
  }
}

extern "C" void kernel_launch(void* const* d_in, const int* in_sizes, int n_in,
                              void* d_out, int out_size, void* d_ws, size_t ws_size,
                              hipStream_t stream) {
  const float* x    = (const float*)d_in[0];
  const float* w    = (const float*)d_in[1];
  const float* bias = (const float*)d_in[2];
  float* y = (float*)d_out;

  u16* wtT = (u16*)d_ws;
  u16* xt  = (u16*)((char*)d_ws + (size_t)C_OUT * KTOT * sizeof(u16)); // +147456 B

  hipLaunchKernelGGL(convert_xw, dim3(50, 64), dim3(256), 0, stream, x, w, xt, wtT);
  hipLaunchKernelGGL(conv_gemm, dim3(OH / 2, N_IMG), dim3(256), 0, stream,
                     xt, wtT, bias, y);
}